// Round 1
// baseline (815.093 us; speedup 1.0000x reference)
//
#include <hip/hip_runtime.h>
#include <math.h>

// Problem constants (from reference)
#define BB 4
#define SS 8192
#define DD 2048
#define RKHS 1024
#define EMBD 128
#define NE 64
#define NTOK (BB * SS)          // 32768

// Workspace layout
//   [0, 512KB)      : remb_t  double[RKHS][NE]   (r-major, e fastest)
//   [512KB, 1MB)    : Cmat    float[DD][NE]      (d-major, e fastest)
//   [1MB, 1MB+512B) : c0      double[NE]
#define REMB_OFF   0
#define CMAT_OFF   (RKHS * NE * 8)            // 524288
#define C0_OFF     (CMAT_OFF + DD * NE * 4)   // 1048576

// ---------------------------------------------------------------------------
// Kernel A: rkhs_emb[e][r] = sum_d embeddings[e][d]*W_exp[r][d] + b_exp[r]
// stored transposed as remb_t[r*64 + e] (double)
// grid = RKHS blocks, 64 threads (one wave). W_exp row is wave-uniform
// (broadcast loads); embeddings (32KB) lives in L1/L2.
// ---------------------------------------------------------------------------
__global__ __launch_bounds__(64) void kernel_rkhs_emb(
    const float* __restrict__ emb, const float* __restrict__ W_exp,
    const float* __restrict__ b_exp, double* __restrict__ remb_t) {
  int r = blockIdx.x;
  int e = threadIdx.x;
  const float* wrow = W_exp + (size_t)r * EMBD;
  const float* erow = emb + (size_t)e * EMBD;
  double acc = (double)b_exp[r];
#pragma unroll 8
  for (int d = 0; d < EMBD; ++d)
    acc += (double)erow[d] * (double)wrow[d];
  remb_t[(size_t)r * NE + e] = acc;
}

// ---------------------------------------------------------------------------
// Kernel B: C[d][e] = sum_r W_hid[r][d] * remb_t[r][e]   (fp64 acc -> fp32)
//           c0[e]   = sum_r b_hid[r]    * remb_t[r][e]   (fp64)
// grid = 513 blocks x 256 threads. Blocks 0..511: 4 d's x 64 e's each
// (W_hid read is wave-uniform broadcast; remb_t read is 512B coalesced,
// L2-resident). Block 512: c0.
// ---------------------------------------------------------------------------
__global__ __launch_bounds__(256) void kernel_proj(
    const float* __restrict__ W_hid, const float* __restrict__ b_hid,
    const double* __restrict__ remb_t, float* __restrict__ Cmat,
    double* __restrict__ c0) {
  int u = threadIdx.x;
  if (blockIdx.x == 512) {
    if (u < NE) {
      double acc = 0.0;
#pragma unroll 8
      for (int r = 0; r < RKHS; ++r)
        acc += (double)b_hid[r] * remb_t[(size_t)r * NE + u];
      c0[u] = acc;
    }
    return;
  }
  int e = u & 63;
  int d = blockIdx.x * 4 + (u >> 6);
  double acc = 0.0;
#pragma unroll 4
  for (int r = 0; r < RKHS; ++r)
    acc += (double)W_hid[(size_t)r * DD + d] * remb_t[(size_t)r * NE + e];
  Cmat[(size_t)d * NE + e] = (float)acc;
}

// ---------------------------------------------------------------------------
// Kernel C: main fused router.
//   logits[t][e] = sum_d input[t][d] * C[d][e] + c0[e]   (fp64 accumulate)
//   then per-token top-2 (lowest-index tie-break, matching lax.top_k),
//   routing weights = softmax over the two top logits (full-softmax Z
//   cancels under the top-k renorm), selected indices written as floats.
//
// 512 blocks x 256 threads. Block covers 64 tokens x all 64 experts.
// K staged in Dc=32 chunks: input tile as double[64][33] (pad -> ds_read_b64
// conflict-free), C tile as double[32][64] (reads are 2-address broadcast).
// Thread u: tgrp=u&31 -> tokens {tgrp, tgrp+32}; e0=(u>>5)*8 -> 8 experts.
// 16 fp64 accumulators/thread. LDS = 16896 + 16384 = 33280 B.
// ---------------------------------------------------------------------------
#define DC 32
#define AIN_STRIDE 33
#define AIN_BYTES (64 * AIN_STRIDE * 8)   // 16896
#define CL_BYTES (DC * NE * 8)            // 16384

__global__ __launch_bounds__(256) void kernel_router(
    const float* __restrict__ input, const float* __restrict__ Cmat,
    const double* __restrict__ c0, float* __restrict__ out) {
  __shared__ __align__(16) char smem[AIN_BYTES + CL_BYTES];
  double* Ain = (double*)smem;               // [64][33]
  double* Cl = (double*)(smem + AIN_BYTES);  // [32][64]
  float* Lg = (float*)smem;                  // overlay: [64][65] logits

  const int u = threadIdx.x;
  const int tgrp = u & 31;
  const int e0 = (u >> 5) * 8;
  const size_t tok0 = (size_t)blockIdx.x * 64;

  double acc0[8], acc1[8];
#pragma unroll
  for (int j = 0; j < 8; ++j) {
    double c = c0[e0 + j];
    acc0[j] = c;
    acc1[j] = c;
  }

  for (int ch = 0; ch < DD / DC; ++ch) {
    const int d0 = ch * DC;
    // stage input tile: 64 tokens x 32 d, fp32 -> fp64
#pragma unroll
    for (int p = 0; p < 2; ++p) {
      int q = p * 256 + u;          // 0..511
      int t = q >> 3;               // 0..63
      int dv = (q & 7) * 4;
      const float4 v =
          *(const float4*)(input + (tok0 + t) * DD + d0 + dv);
      double* dst = &Ain[t * AIN_STRIDE + dv];
      dst[0] = v.x; dst[1] = v.y; dst[2] = v.z; dst[3] = v.w;
    }
    // stage C tile: 32 d x 64 e, fp32 -> fp64
#pragma unroll
    for (int p = 0; p < 2; ++p) {
      int q = p * 256 + u;
      int dd = q >> 4;              // 0..31
      int ev = (q & 15) * 4;
      const float4 v = *(const float4*)(Cmat + (size_t)(d0 + dd) * NE + ev);
      double* dst = &Cl[dd * NE + ev];
      dst[0] = v.x; dst[1] = v.y; dst[2] = v.z; dst[3] = v.w;
    }
    __syncthreads();
#pragma unroll 8
    for (int dj = 0; dj < DC; ++dj) {
      const double a0 = Ain[tgrp * AIN_STRIDE + dj];
      const double a1 = Ain[(tgrp + 32) * AIN_STRIDE + dj];
      const double* cp = &Cl[dj * NE + e0];
#pragma unroll
      for (int j = 0; j < 8; ++j) {
        const double cv = cp[j];
        acc0[j] += a0 * cv;
        acc1[j] += a1 * cv;
      }
    }
    __syncthreads();
  }

  // dump logits (fp32) to LDS, overlaying the input tile area
#pragma unroll
  for (int j = 0; j < 8; ++j) {
    Lg[tgrp * 65 + e0 + j] = (float)acc0[j];
    Lg[(tgrp + 32) * 65 + e0 + j] = (float)acc1[j];
  }
  __syncthreads();

  if (u < 64) {
    const float* lr = &Lg[u * 65];
    float m1 = lr[0];
    int i1 = 0;
#pragma unroll 8
    for (int e = 1; e < NE; ++e) {
      float v = lr[e];
      if (v > m1) { m1 = v; i1 = e; }
    }
    int i2 = (i1 == 0) ? 1 : 0;
    float m2 = lr[i2];
#pragma unroll 8
    for (int e = 0; e < NE; ++e) {
      if (e == i1) continue;
      float v = lr[e];
      if (v > m2) { m2 = v; i2 = e; }
    }
    // routing weights: softmax over the two selected logits
    double ex = exp((double)m2 - (double)m1);
    double denom = 1.0 + ex;
    float rw1 = (float)(1.0 / denom);
    float rw2 = (float)(ex / denom);

    const size_t tg = tok0 + u;
    *(float2*)(out + tg * 2) = make_float2((float)i1, (float)i2);
    *(float2*)(out + (size_t)NTOK * 2 + tg * 2) = make_float2(rw1, rw2);
  }
  // aux loss is analytically constant: (K/E * 1/2) * E^2 = 64.0
  if (blockIdx.x == 0 && u == 0) out[(size_t)NTOK * 4] = 64.0f;
}

// ---------------------------------------------------------------------------
extern "C" void kernel_launch(void* const* d_in, const int* in_sizes, int n_in,
                              void* d_out, int out_size, void* d_ws,
                              size_t ws_size, hipStream_t stream) {
  const float* input = (const float*)d_in[0];      // [4,8192,2048]
  const float* W_hid = (const float*)d_in[1];      // [1024,2048]
  const float* b_hid = (const float*)d_in[2];      // [1024]
  const float* W_exp = (const float*)d_in[3];      // [1024,128]
  const float* b_exp = (const float*)d_in[4];      // [1024]
  const float* emb = (const float*)d_in[5];        // [64,128]
  float* out = (float*)d_out;

  double* remb_t = (double*)((char*)d_ws + REMB_OFF);
  float* Cmat = (float*)((char*)d_ws + CMAT_OFF);
  double* c0 = (double*)((char*)d_ws + C0_OFF);

  kernel_rkhs_emb<<<RKHS, 64, 0, stream>>>(emb, W_exp, b_exp, remb_t);
  kernel_proj<<<513, 256, 0, stream>>>(W_hid, b_hid, remb_t, Cmat, c0);
  kernel_router<<<NTOK / 64, 256, 0, stream>>>(input, Cmat, c0, out);
}

// Round 2
// 485.039 us; speedup vs baseline: 1.6805x; 1.6805x over previous
//
#include <hip/hip_runtime.h>
#include <math.h>

// Problem constants (from reference)
#define BB 4
#define SS 8192
#define DD 2048
#define RKHS 1024
#define EMBD 128
#define NE 64
#define NTOK (BB * SS)          // 32768
#define NKK (DD / 32)           // 64 K-steps of 32

typedef __attribute__((ext_vector_type(8))) _Float16 half8;
typedef __attribute__((ext_vector_type(2))) _Float16 half2v;
typedef __attribute__((ext_vector_type(4))) float f32x4;

// Workspace layout (max concurrent 768KB+256B; round 1 proved ws >= 1.05MB):
//   remb  fp32[1024][64]        @ 0        [0, 256K)    live K1->K2
//   Cpack half2(hi,lo)[2048][64]@ 256K     [256K,768K)  live K2->K3 (scaled 2^12)
//   Bsw   uint4[32768]          @ 0        [0, 512K)    live K3->K4 (overwrites remb)
//   c0    fp32[64]              @ 768K                  live K2->K4
#define REMB_OFF  0
#define CPACK_OFF (256 * 1024)
#define BSW_OFF   0
#define C0_OFF    (768 * 1024)

// ---------------------------------------------------------------------------
// K1: remb[r][e] = sum_d embeddings[e][d]*W_exp[r][d] + b_exp[r]  (fp64 acc)
// grid 256 x 256: block covers 4 r's x 64 e's.
// ---------------------------------------------------------------------------
__global__ __launch_bounds__(256) void k_emb(
    const float* __restrict__ emb, const float* __restrict__ W_exp,
    const float* __restrict__ b_exp, float* __restrict__ remb) {
  int u = threadIdx.x;
  int e = u & 63;
  int r = blockIdx.x * 4 + (u >> 6);
  const float* er = emb + (size_t)e * EMBD;
  const float* wr = W_exp + (size_t)r * EMBD;
  double a = (double)b_exp[r];
#pragma unroll 8
  for (int d = 0; d < EMBD; ++d) a += (double)er[d] * (double)wr[d];
  remb[(size_t)r * NE + e] = (float)a;
}

// ---------------------------------------------------------------------------
// K2: C[d][e] = sum_r W_hid[r][d]*remb[r][e]  (fp64 acc, r split 4-way + LDS
// reduce), stored as fp16 (hi,lo) pair of C*4096.  Block d==2048 computes
// c0[e] = sum_r b_hid[r]*remb[r][e] (unscaled fp32).
// ---------------------------------------------------------------------------
__global__ __launch_bounds__(256) void k_proj(
    const float* __restrict__ W_hid, const float* __restrict__ b_hid,
    const float* __restrict__ remb, half2v* __restrict__ Cpack,
    float* __restrict__ c0) {
  __shared__ double red[4][64];
  int u = threadIdx.x;
  int e = u & 63, rq = u >> 6;
  int d = blockIdx.x;  // 0..2047 -> C row; 2048 -> c0
  double acc = 0.0;
  if (d < DD) {
#pragma unroll 8
    for (int i = 0; i < 256; ++i) {
      int r = rq * 256 + i;
      acc += (double)W_hid[(size_t)r * DD + d] * (double)remb[(size_t)r * NE + e];
    }
  } else {
#pragma unroll 8
    for (int i = 0; i < 256; ++i) {
      int r = rq * 256 + i;
      acc += (double)b_hid[r] * (double)remb[(size_t)r * NE + e];
    }
  }
  red[rq][e] = acc;
  __syncthreads();
  if (u < 64) {
    double s = red[0][u] + red[1][u] + red[2][u] + red[3][u];
    if (d < DD) {
      float c = (float)(s * 4096.0);  // scale by 2^12: keeps lo out of fp16 subnormals
      _Float16 hi = (_Float16)c;
      _Float16 lo = (_Float16)(c - (float)hi);
      half2v p; p.x = hi; p.y = lo;
      Cpack[(size_t)d * NE + u] = p;
    } else {
      c0[u] = (float)s;
    }
  }
}

// ---------------------------------------------------------------------------
// K3: pre-swizzle Cpack into MFMA B-fragment order.
// Fragment for (kk, group g, half h): lane l holds 8 fp16 =
//   C16[k = kk*32 + (l>>4)*8 + j][n = g*16 + (l&15)], j=0..7, packed 16B.
// Bsw uint4 index = ((kk*4+g)*2+h)*64 + l  == flat thread id.
// ---------------------------------------------------------------------------
__global__ __launch_bounds__(256) void k_swz(
    const half2v* __restrict__ Cpack, uint4* __restrict__ Bsw) {
  int flat = blockIdx.x * 256 + threadIdx.x;   // 0..32767
  int lane = flat & 63;
  int h = (flat >> 6) & 1;
  int g = (flat >> 7) & 3;
  int kk = flat >> 9;
  int n = g * 16 + (lane & 15);
  int kb = kk * 32 + ((lane >> 4) & 3) * 8;
  half8 v;
#pragma unroll
  for (int j = 0; j < 8; ++j) {
    half2v p = Cpack[(size_t)(kb + j) * NE + n];
    v[j] = h ? p.y : p.x;
  }
  Bsw[flat] = __builtin_bit_cast(uint4, v);
}

// ---------------------------------------------------------------------------
// K4: main router. 2048 blocks x 64 threads (1 wave = 16 tokens x 64 experts).
// Barrier-free K-loop: A streamed from global per-lane (32B/step, each input
// byte read exactly once), split to fp16 hi/lo in registers; B-fragments
// loaded pre-swizzled from L2-resident Bsw. 3-pass split MFMA (hh, hl, lh)
// into fp32 acc. Epilogue: logits -> LDS, lanes 0..15 top-2 + softmax.
// ---------------------------------------------------------------------------
__global__ __launch_bounds__(64, 4) void kernel_router(
    const float* __restrict__ in, const uint4* __restrict__ Bsw,
    const float* __restrict__ c0, float* __restrict__ out) {
  __shared__ float Lg[16][65];
  const int l = threadIdx.x;
  const size_t tok0 = (size_t)blockIdx.x * 16;
  const int q = (l >> 4) & 3;                 // quad
  const float* arow = in + (tok0 + (l & 15)) * DD + q * 8;

  f32x4 acc0 = {0.f, 0.f, 0.f, 0.f};
  f32x4 acc1 = {0.f, 0.f, 0.f, 0.f};
  f32x4 acc2 = {0.f, 0.f, 0.f, 0.f};
  f32x4 acc3 = {0.f, 0.f, 0.f, 0.f};

#pragma unroll 2
  for (int kk = 0; kk < NKK; ++kk) {
    const float4 a0 = *(const float4*)(arow + kk * 32);
    const float4 a1 = *(const float4*)(arow + kk * 32 + 4);
    const uint4* bq = Bsw + (size_t)kk * 512 + l;
    const uint4 h0 = bq[0],   l0 = bq[64];
    const uint4 h1 = bq[128], l1 = bq[192];
    const uint4 h2 = bq[256], l2 = bq[320];
    const uint4 h3 = bq[384], l3 = bq[448];

    const float av[8] = {a0.x, a0.y, a0.z, a0.w, a1.x, a1.y, a1.z, a1.w};
    half8 ah, al;
#pragma unroll
    for (int j = 0; j < 8; ++j) {
      _Float16 hi = (_Float16)av[j];
      ah[j] = hi;
      al[j] = (_Float16)(av[j] - (float)hi);
    }
    const half8 bh0 = __builtin_bit_cast(half8, h0), bl0 = __builtin_bit_cast(half8, l0);
    const half8 bh1 = __builtin_bit_cast(half8, h1), bl1 = __builtin_bit_cast(half8, l1);
    const half8 bh2 = __builtin_bit_cast(half8, h2), bl2 = __builtin_bit_cast(half8, l2);
    const half8 bh3 = __builtin_bit_cast(half8, h3), bl3 = __builtin_bit_cast(half8, l3);

    acc0 = __builtin_amdgcn_mfma_f32_16x16x32_f16(ah, bh0, acc0, 0, 0, 0);
    acc1 = __builtin_amdgcn_mfma_f32_16x16x32_f16(ah, bh1, acc1, 0, 0, 0);
    acc2 = __builtin_amdgcn_mfma_f32_16x16x32_f16(ah, bh2, acc2, 0, 0, 0);
    acc3 = __builtin_amdgcn_mfma_f32_16x16x32_f16(ah, bh3, acc3, 0, 0, 0);
    acc0 = __builtin_amdgcn_mfma_f32_16x16x32_f16(al, bh0, acc0, 0, 0, 0);
    acc1 = __builtin_amdgcn_mfma_f32_16x16x32_f16(al, bh1, acc1, 0, 0, 0);
    acc2 = __builtin_amdgcn_mfma_f32_16x16x32_f16(al, bh2, acc2, 0, 0, 0);
    acc3 = __builtin_amdgcn_mfma_f32_16x16x32_f16(al, bh3, acc3, 0, 0, 0);
    acc0 = __builtin_amdgcn_mfma_f32_16x16x32_f16(ah, bl0, acc0, 0, 0, 0);
    acc1 = __builtin_amdgcn_mfma_f32_16x16x32_f16(ah, bl1, acc1, 0, 0, 0);
    acc2 = __builtin_amdgcn_mfma_f32_16x16x32_f16(ah, bl2, acc2, 0, 0, 0);
    acc3 = __builtin_amdgcn_mfma_f32_16x16x32_f16(ah, bl3, acc3, 0, 0, 0);
  }

  // epilogue: descale, add bias, dump to LDS.
  // C/D layout (m89-verified): col = lane&15, row = (lane>>4)*4 + reg
  {
    const float inv = 1.0f / 4096.0f;
#pragma unroll
    for (int r = 0; r < 4; ++r) {
      Lg[q * 4 + r][0 * 16 + (l & 15)] = acc0[r] * inv + c0[0 * 16 + (l & 15)];
      Lg[q * 4 + r][1 * 16 + (l & 15)] = acc1[r] * inv + c0[1 * 16 + (l & 15)];
      Lg[q * 4 + r][2 * 16 + (l & 15)] = acc2[r] * inv + c0[2 * 16 + (l & 15)];
      Lg[q * 4 + r][3 * 16 + (l & 15)] = acc3[r] * inv + c0[3 * 16 + (l & 15)];
    }
  }
  __syncthreads();

  if (l < 16) {
    const float* lr = &Lg[l][0];
    float m1 = lr[0];
    int i1 = 0;
#pragma unroll 8
    for (int e = 1; e < NE; ++e) {
      float v = lr[e];
      if (v > m1) { m1 = v; i1 = e; }
    }
    int i2 = (i1 == 0) ? 1 : 0;
    float m2 = lr[i2];
#pragma unroll 8
    for (int e = 0; e < NE; ++e) {
      if (e == i1) continue;
      float v = lr[e];
      if (v > m2) { m2 = v; i2 = e; }
    }
    double ex = exp((double)m2 - (double)m1);
    double denom = 1.0 + ex;
    float rw1 = (float)(1.0 / denom);
    float rw2 = (float)(ex / denom);

    const size_t tg = tok0 + l;
    *(float2*)(out + tg * 2) = make_float2((float)i1, (float)i2);
    *(float2*)(out + (size_t)NTOK * 2 + tg * 2) = make_float2(rw1, rw2);
  }
  // aux loss analytically constant: (K/E * 1/2) * E^2 = 64.0
  if (blockIdx.x == 0 && l == 0) out[(size_t)NTOK * 4] = 64.0f;
}

// ---------------------------------------------------------------------------
extern "C" void kernel_launch(void* const* d_in, const int* in_sizes, int n_in,
                              void* d_out, int out_size, void* d_ws,
                              size_t ws_size, hipStream_t stream) {
  const float* input = (const float*)d_in[0];   // [4,8192,2048]
  const float* W_hid = (const float*)d_in[1];   // [1024,2048]
  const float* b_hid = (const float*)d_in[2];   // [1024]
  const float* W_exp = (const float*)d_in[3];   // [1024,128]
  const float* b_exp = (const float*)d_in[4];   // [1024]
  const float* emb = (const float*)d_in[5];     // [64,128]
  float* out = (float*)d_out;

  float* remb = (float*)((char*)d_ws + REMB_OFF);
  half2v* Cpack = (half2v*)((char*)d_ws + CPACK_OFF);
  uint4* Bsw = (uint4*)((char*)d_ws + BSW_OFF);
  float* c0 = (float*)((char*)d_ws + C0_OFF);

  k_emb<<<RKHS / 4, 256, 0, stream>>>(emb, W_exp, b_exp, remb);
  k_proj<<<DD + 1, 256, 0, stream>>>(W_hid, b_hid, remb, Cpack, c0);
  k_swz<<<128, 256, 0, stream>>>(Cpack, Bsw);
  kernel_router<<<NTOK / 16, 64, 0, stream>>>(input, Bsw, c0, out);
}